// Round 9
// baseline (330.754 us; speedup 1.0000x reference)
//
#include <hip/hip_runtime.h>
#include <hip/hip_bf16.h>
#include <stdint.h>

// Problem constants
#define BATCH   8192
#define IN_DIM  1024
#define N_HID   2048
#define OUT_DIM 256
#define SRC_DIM 3072

// Tiling
#define C     32                   // source columns per chunk
#define RB    8                    // rows per row-block (= rows per wave)
#define BT    256                  // batch per block (4/lane)
#define S1_CH (IN_DIM / C)         // 32
#define S1_RB (N_HID / RB)         // 256
#define S2_CH (SRC_DIM / C)        // 96
#define S2_RB (OUT_DIM / RB)       // 32
#define NSEG1 (S1_RB * S1_CH)      // 8192
#define NSEG2 (S2_RB * S2_CH)      // 3072
#define ZSLOT 128                  // A-tile zero page (pad byte 0x80)
#define SEG_U32 80                 // segment stride (320 B; up to 15 ov planes)
#define ABUF_U32 ((4 * C + 1) * 128)  // 16512 u32 = 64.5 KB A-tile

// Segment format v6 (RB=8, granule-2 overflow):
//   u32[0..3]   plane-0: row r -> u16 at byte 2r (2 slot bytes, pad 0x80)
//   overflow planes p=1..15 at u32 4+5(p-1), stride 5:
//     [0]    = 8-bit row mask (rows with n > 2p)
//     [1..4] = u16 per row: 2 slot bytes for overflow idx 2(p-1), 2(p-1)+1
// R1: vector gating ~70 VALU/slot -> plane-0 unconditional, pads -> zero page.
// R2: BT=256 halved per-elem VALU.
// R3: dbuf+1-barrier fixed 1-block skew (needed only at low occupancy).
// R4 (9297us): long-lived arrays -> acc SCRATCH spill. Load inside guards.
// R5-R7: granule-2 + pk_add wins; RFL/sched_barrier neutral.
// R8 LESSON: occupancy stuck at 44% with 66KB LDS + 512 blocks => limiter is
// the UNIFIED VGPR+AGPR file: accs (64 regs) live in AGPRs (VGPR_Count 48-52
// reports arch only); 48+64=112 > 64 => 16 waves/CU hard cap since R2.
// R9: RB=8 (acc 32) + __launch_bounds__(1024,8) => <=64 total regs =>
// 2 blocks/CU (32 waves). Single-buf A-tile (129KB/CU for 2 blocks),
// 2-barrier loop (cheap at 2 blocks/CU -- R0 regime). Acts recompute x2
// (16 row-splits) is the accepted tax (~+14% VALU).
// VERIFY: Occupancy ~80. DANGER: WRITE_SIZE >> 33MB = spill => revert.

#define RFL(x) __builtin_amdgcn_readfirstlane((uint32_t)(x))

// ---------------------------------------------------------------------------
__global__ void k_prep(const int* __restrict__ mat,
                       uint32_t* __restrict__ seg1, uint32_t* __restrict__ seg2,
                       uint32_t* __restrict__ hdr1, uint32_t* __restrict__ hdr2) {
    int wid  = (blockIdx.x * blockDim.x + threadIdx.x) >> 6;
    int lane = threadIdx.x & 63;
    if (wid >= NSEG1 + NSEG2) return;

    int row0, col0;
    uint32_t *seg, *hdr;
    if (wid < NSEG1) {
        int rb = wid / S1_CH, ch = wid % S1_CH;
        row0 = rb * RB;          col0 = ch * C;
        seg = seg1 + (size_t)wid * SEG_U32;  hdr = hdr1 + wid;
    } else {
        int s  = wid - NSEG1;
        int rb = s / S2_CH, ch = s % S2_CH;
        row0 = N_HID + rb * RB;  col0 = ch * C;
        seg = seg2 + (size_t)s * SEG_U32;    hdr = hdr2 + s;
    }

    int n = 0;
    if (lane < RB) {
        const int4* m4 = (const int4*)(mat + (size_t)(row0 + lane) * SRC_DIM + col0);
        uint8_t* sb = (uint8_t*)seg;
        #pragma unroll
        for (int cc = 0; cc < 8; cc++) {
            int4 q4 = m4[cc];
            int codes[4] = {q4.x, q4.y, q4.z, q4.w};
            #pragma unroll
            for (int k = 0; k < 4; k++) {
                int code = codes[k];
                if (code != 0) {
                    int c = cc * 4 + k;
                    uint8_t slot = (uint8_t)((code - 1) * C + c);
                    if (n < 2) {
                        sb[2 * lane + n] = slot;           // plane-0 u16
                    } else {
                        int j  = n - 2;                    // overflow index
                        int pl = j >> 1;                   // 0-based ov plane
                        sb[(size_t)(4 + 5 * pl + 1 + (lane >> 1)) * 4
                           + (lane & 1) * 2 + (j & 1)] = slot;
                    }
                    n++;
                }
            }
        }
    }
    int m = n;
    #pragma unroll
    for (int d = 1; d < 64; d <<= 1) m = max(m, __shfl_xor(m, d));
    uint32_t Wv = (m <= 2) ? 1u : 1u + (uint32_t)((m - 1) >> 1);

    for (uint32_t p = 1; p < Wv; p++) {
        unsigned long long b = __ballot(n > (int)(2 * p));
        if (lane == 0) seg[4 + 5 * (p - 1)] = (uint32_t)(b & 0xFFu);
    }
    if (lane == 0) *hdr = Wv;
}

// ---------------------------------------------------------------------------
// k_xt: transpose x[8192][1024] -> x_t[1024][8192] (fp32), 64x64 LDS tiles.
// ---------------------------------------------------------------------------
__global__ __launch_bounds__(256) void k_xt(const float* __restrict__ x,
                                            float* __restrict__ x_t) {
    __shared__ float t[64][65];
    const int b0 = blockIdx.x * 64, c0 = blockIdx.y * 64;
    {
        int r  = threadIdx.x >> 4;
        int cq = (threadIdx.x & 15) * 4;
        #pragma unroll
        for (int k = 0; k < 4; k++) {
            int rr = r + 16 * k;
            float4 v = *(const float4*)&x[(size_t)(b0 + rr) * IN_DIM + c0 + cq];
            t[rr][cq + 0] = v.x; t[rr][cq + 1] = v.y;
            t[rr][cq + 2] = v.z; t[rr][cq + 3] = v.w;
        }
    }
    __syncthreads();
    {
        int bq  = (threadIdx.x & 15) * 4;
        int cc0 = threadIdx.x >> 4;
        #pragma unroll
        for (int k = 0; k < 4; k++) {
            int cc = cc0 + 16 * k;
            float4 v;
            v.x = t[bq + 0][cc]; v.y = t[bq + 1][cc];
            v.z = t[bq + 2][cc]; v.w = t[bq + 3][cc];
            *(float4*)&x_t[(size_t)(c0 + cc) * BATCH + b0 + bq] = v;
        }
    }
}

typedef float v2f __attribute__((ext_vector_type(2)));

// pack two floats as bf16 pair: low16 = first, high16 = second
__device__ __forceinline__ uint32_t pack2(float a, float b) {
    __hip_bfloat162 h = __float22bfloat162_rn(make_float2(a, b));
    union { __hip_bfloat162 h2; uint32_t u; } u;
    u.h2 = h;
    return u.u;
}

__device__ __forceinline__ float rcp_f(float x) { return __builtin_amdgcn_rcpf(x); }

// write 4 activation slots for column c, 4 batches per lane (v pre-scaled by w).
// Trans budget/elem: 1 v_exp + 2 v_rcp.
__device__ __forceinline__ void write_acts4(uint32_t* As, int c, int lane, float4 v) {
    *(uint2*)&As[(size_t)(0 * C + c) * 128 + 2 * lane] =
        make_uint2(pack2(v.x, v.y), pack2(v.z, v.w));
    *(uint2*)&As[(size_t)(1 * C + c) * 128 + 2 * lane] =
        make_uint2(pack2(fmaxf(v.x, 0.0f), fmaxf(v.y, 0.0f)),
                   pack2(fmaxf(v.z, 0.0f), fmaxf(v.w, 0.0f)));
    float ex = __expf(-v.x), ey = __expf(-v.y);
    float ez = __expf(-v.z), ew = __expf(-v.w);
    float tx = fmaf(2.0f, rcp_f(fmaf(ex, ex, 1.0f)), -1.0f);
    float ty = fmaf(2.0f, rcp_f(fmaf(ey, ey, 1.0f)), -1.0f);
    float tz = fmaf(2.0f, rcp_f(fmaf(ez, ez, 1.0f)), -1.0f);
    float tw = fmaf(2.0f, rcp_f(fmaf(ew, ew, 1.0f)), -1.0f);
    *(uint2*)&As[(size_t)(2 * C + c) * 128 + 2 * lane] =
        make_uint2(pack2(tx, ty), pack2(tz, tw));
    float sx = rcp_f(1.0f + ex), sy = rcp_f(1.0f + ey);
    float sz = rcp_f(1.0f + ez), sw = rcp_f(1.0f + ew);
    *(uint2*)&As[(size_t)(3 * C + c) * 128 + 2 * lane] =
        make_uint2(pack2(sx, sy), pack2(sz, sw));
}

// one slot: ds_read_b64 -> 2 bf16-pairs -> 2 v_pk_add_f32 (4 batches/lane)
#define SLOT_ACC(R, S)                                                         \
    {                                                                          \
        uint2 q_ = *(const uint2*)&As[(size_t)(S) * 128 + 2 * lane];           \
        v2f ua_, ub_;                                                          \
        ua_.x = __uint_as_float(q_.x << 16);                                   \
        ua_.y = __uint_as_float(q_.x & 0xFFFF0000u);                           \
        ub_.x = __uint_as_float(q_.y << 16);                                   \
        ub_.y = __uint_as_float(q_.y & 0xFFFF0000u);                           \
        accA[R] += ua_;                                                        \
        accB[R] += ub_;                                                        \
    }

// v6 (RB=8): plane-0 = 4 words / 16 slots unconditional (pads -> zero page);
// overflow planes: 8-bit scalar-gated rows, words loaded INSIDE the guard.
#define EDGE_PLANES(SEGBASE, WVAL)                                             \
    {                                                                          \
        const uint32_t* sp_ = (SEGBASE);                                       \
        _Pragma("unroll")                                                      \
        for (int i = 0; i < 4; i++) {                                          \
            uint32_t g = RFL(sp_[i]);                                          \
            SLOT_ACC(2 * i,     g & 255u)                                      \
            SLOT_ACC(2 * i,     (g >> 8) & 255u)                               \
            SLOT_ACC(2 * i + 1, (g >> 16) & 255u)                              \
            SLOT_ACC(2 * i + 1, g >> 24)                                       \
        }                                                                      \
        _Pragma("unroll 1")                                                    \
        for (uint32_t p = 1; p < (WVAL); p++) {                                \
            const uint32_t* pp_ = sp_ + 4 + 5 * (p - 1);                       \
            uint32_t mask = RFL(pp_[0]);                                       \
            _Pragma("unroll")                                                  \
            for (int r = 0; r < RB; r++) {                                     \
                if (mask & (1u << r)) {                                        \
                    uint32_t h_ = RFL(pp_[1 + (r >> 1)]);                      \
                    uint32_t u_ = (r & 1) ? (h_ >> 16) : h_;                   \
                    SLOT_ACC(r, u_ & 255u)                                     \
                    SLOT_ACC(r, (u_ >> 8) & 255u)                              \
                }                                                              \
            }                                                                  \
        }                                                                      \
    }

// ---------------------------------------------------------------------------
// Stage 1: 16 waves x 8 rows = 128 rows; 256 batches per block.
// Grid (32 tiles, 16 row splits) = 512 blocks = 2/CU (32 waves, 129 KB LDS).
// Single-buf A-tile, 2 barriers/chunk (cheap at 2 blocks/CU -- R0 regime).
// ---------------------------------------------------------------------------
__global__ __launch_bounds__(1024, 8) void k_hid(const float* __restrict__ x_t,
                                                 const float* __restrict__ wp,
                                                 const uint32_t* __restrict__ seg1,
                                                 const uint32_t* __restrict__ hdr1,
                                                 __hip_bfloat16* __restrict__ hidden_t) {
    __shared__ uint32_t As[ABUF_U32];           // 64.5 KB

    const float w  = wp[0];
    const int tile = blockIdx.x;                // 0..31
    const int lane = threadIdx.x & 63;
    const int wv   = __builtin_amdgcn_readfirstlane(threadIdx.x >> 6); // 0..15
    const int rb   = blockIdx.y * 16 + wv;      // row-block 0..255
    const int b0   = tile * BT;

    if (threadIdx.x < 128) As[ZSLOT * 128 + threadIdx.x] = 0u;

    v2f accA[RB], accB[RB];
    #pragma unroll
    for (int r = 0; r < RB; r++) {
        accA[r] = (v2f)0.0f;
        accB[r] = (v2f)0.0f;
    }

    // prefetch chunk 0: each wave owns 2 columns, 4 batches/lane
    float4 v[2];
    #pragma unroll
    for (int j = 0; j < 2; j++) {
        int gcol = wv * 2 + j;
        const float2* xp = (const float2*)&x_t[(size_t)gcol * BATCH + b0];
        float2 u0 = xp[lane], u1 = xp[64 + lane];
        v[j] = make_float4(w * u0.x, w * u0.y, w * u1.x, w * u1.y);
    }

    #pragma unroll 1
    for (int ch = 0; ch < S1_CH; ch++) {
        __syncthreads();                        // edge(ch-1) done (WAR)
        write_acts4(As, wv * 2 + 0, lane, v[0]);
        write_acts4(As, wv * 2 + 1, lane, v[1]);
        __syncthreads();                        // acts visible
        if (ch + 1 < S1_CH) {                   // prefetch next chunk
            #pragma unroll
            for (int j = 0; j < 2; j++) {
                int gcol = (ch + 1) * C + wv * 2 + j;
                const float2* xp = (const float2*)&x_t[(size_t)gcol * BATCH + b0];
                float2 u0 = xp[lane], u1 = xp[64 + lane];
                v[j] = make_float4(w * u0.x, w * u0.y, w * u1.x, w * u1.y);
            }
        }
        int sidx = rb * S1_CH + ch;
        uint32_t W = RFL(hdr1[sidx]);
        EDGE_PLANES(seg1 + (size_t)sidx * SEG_U32, W)
    }

    const int row0 = rb * RB;
    #pragma unroll
    for (int r = 0; r < RB; r++) {
        *(uint32_t*)&hidden_t[(size_t)(row0 + r) * BATCH + b0 + 2 * lane] =
            pack2(accA[r].x, accA[r].y);
        *(uint32_t*)&hidden_t[(size_t)(row0 + r) * BATCH + b0 + 128 + 2 * lane] =
            pack2(accB[r].x, accB[r].y);
    }
}

// source loader for stage 2 (x_t fp32 or hidden_t bf16), pre-scaled by w
__device__ __forceinline__ float4 load_src4(const float* __restrict__ x_t,
                                            const __hip_bfloat16* __restrict__ hidden_t,
                                            int gcol, int b0, int lane, float w) {
    if (gcol < IN_DIM) {
        const float2* xp = (const float2*)&x_t[(size_t)gcol * BATCH + b0];
        float2 u0 = xp[lane], u1 = xp[64 + lane];
        return make_float4(w * u0.x, w * u0.y, w * u1.x, w * u1.y);
    } else {
        const uint16_t* hp = (const uint16_t*)&hidden_t[(size_t)(gcol - IN_DIM) * BATCH + b0];
        uint32_t q0 = *(const uint32_t*)&hp[2 * lane];
        uint32_t q1 = *(const uint32_t*)&hp[128 + 2 * lane];
        return make_float4(w * __uint_as_float(q0 << 16),
                           w * __uint_as_float(q0 & 0xFFFF0000u),
                           w * __uint_as_float(q1 << 16),
                           w * __uint_as_float(q1 & 0xFFFF0000u));
    }
}

// ---------------------------------------------------------------------------
// Stage 2: 16 waves x 8 rows = 128 rows; grid (32 tiles, 2 row groups,
// 8 chunk groups of 12) = 512 blocks = 2/CU. Single-buf, 2 barriers/chunk.
// Partials bf16-packed [cg][row][b/2].
// ---------------------------------------------------------------------------
__global__ __launch_bounds__(1024, 8) void k_out(const float* __restrict__ x_t,
                                                 const __hip_bfloat16* __restrict__ hidden_t,
                                                 const float* __restrict__ wp,
                                                 const uint32_t* __restrict__ seg2,
                                                 const uint32_t* __restrict__ hdr2,
                                                 uint32_t* __restrict__ partials) {
    __shared__ uint32_t As[ABUF_U32];

    const float w  = wp[0];
    const int tile = blockIdx.x;                // 0..31
    const int rg   = blockIdx.y;                // 0..1
    const int cg   = blockIdx.z;                // 0..7
    const int lane = threadIdx.x & 63;
    const int wv   = __builtin_amdgcn_readfirstlane(threadIdx.x >> 6); // 0..15
    const int rb   = rg * 16 + wv;              // row-block 0..31
    const int b0   = tile * BT;

    if (threadIdx.x < 128) As[ZSLOT * 128 + threadIdx.x] = 0u;

    v2f accA[RB], accB[RB];
    #pragma unroll
    for (int r = 0; r < RB; r++) {
        accA[r] = (v2f)0.0f;
        accB[r] = (v2f)0.0f;
    }

    float4 v[2];
    #pragma unroll
    for (int j = 0; j < 2; j++)
        v[j] = load_src4(x_t, hidden_t, (cg * 12) * C + wv * 2 + j, b0, lane, w);

    #pragma unroll 1
    for (int cj = 0; cj < 12; cj++) {
        int ch = cg * 12 + cj;
        __syncthreads();
        write_acts4(As, wv * 2 + 0, lane, v[0]);
        write_acts4(As, wv * 2 + 1, lane, v[1]);
        __syncthreads();
        if (cj + 1 < 12) {
            #pragma unroll
            for (int j = 0; j < 2; j++)
                v[j] = load_src4(x_t, hidden_t, (ch + 1) * C + wv * 2 + j, b0, lane, w);
        }
        int sidx = rb * S2_CH + ch;
        uint32_t W = RFL(hdr2[sidx]);
        EDGE_PLANES(seg2 + (size_t)sidx * SEG_U32, W)
    }

    #pragma unroll
    for (int r = 0; r < RB; r++) {
        size_t base = ((size_t)cg * OUT_DIM + rb * RB + r) * (BATCH / 2) + (b0 >> 1);
        partials[base + lane]      = pack2(accA[r].x, accA[r].y);
        partials[base + 64 + lane] = pack2(accB[r].x, accB[r].y);
    }
}

// ---------------------------------------------------------------------------
// k_sum: reduce 8 bf16-packed partial planes + transpose -> out[b][r].
// Block: 128 batches x 16 rows. Grid (64, 16).
// ---------------------------------------------------------------------------
__global__ __launch_bounds__(256) void k_sum(const uint32_t* __restrict__ partials,
                                             float* __restrict__ out) {
    __shared__ float t[16][130];
    const int b0 = blockIdx.x * 128, r0 = blockIdx.y * 16;
    const int lane = threadIdx.x & 63;
    const int g4   = threadIdx.x >> 6;          // 0..3

    #pragma unroll
    for (int k = 0; k < 4; k++) {
        int rr = g4 * 4 + k;
        float sx = 0.0f, sy = 0.0f;
        #pragma unroll
        for (int cg = 0; cg < 8; cg++) {
            uint32_t q = partials[((size_t)cg * OUT_DIM + r0 + rr) * (BATCH / 2)
                                  + (b0 >> 1) + lane];
            sx += __uint_as_float(q << 16);
            sy += __uint_as_float(q & 0xFFFF0000u);
        }
        t[rr][2 * lane]     = sx;
        t[rr][2 * lane + 1] = sy;
    }
    __syncthreads();
    #pragma unroll
    for (int k = 0; k < 2; k++) {
        int idx = threadIdx.x + 256 * k;        // 0..511
        int bb = idx >> 2, rq = idx & 3;
        float4 v;
        v.x = t[rq * 4 + 0][bb];
        v.y = t[rq * 4 + 1][bb];
        v.z = t[rq * 4 + 2][bb];
        v.w = t[rq * 4 + 3][bb];
        *(float4*)&out[(size_t)(b0 + bb) * OUT_DIM + r0 + rq * 4] = v;
    }
}

// ---------------------------------------------------------------------------
extern "C" void kernel_launch(void* const* d_in, const int* in_sizes, int n_in,
                              void* d_out, int out_size, void* d_ws, size_t ws_size,
                              hipStream_t stream) {
    const float* x   = (const float*)d_in[0];
    const float* w   = (const float*)d_in[1];
    const int*   mat = (const int*)d_in[2];
    float* out = (float*)d_out;

    uint8_t* ws = (uint8_t*)d_ws;
    size_t off = 0;
    __hip_bfloat16* hidden_t = (__hip_bfloat16*)(ws + off);
    off += (size_t)BATCH * N_HID * 2;                                          // 33.6 MB
    float* x_t = (float*)(ws + off);        off += (size_t)IN_DIM * BATCH * 4; // 33.6 MB
    uint32_t* seg1 = (uint32_t*)(ws + off); off += (size_t)NSEG1 * SEG_U32 * 4;//  2.62 MB
    uint32_t* seg2 = (uint32_t*)(ws + off); off += (size_t)NSEG2 * SEG_U32 * 4;//  0.98 MB
    uint32_t* hdr1 = (uint32_t*)(ws + off); off += (size_t)NSEG1 * 4;
    uint32_t* hdr2 = (uint32_t*)(ws + off); off += (size_t)NSEG2 * 4;
    uint32_t* partials = (uint32_t*)(ws + off);
    off += (size_t)8 * OUT_DIM * (BATCH / 2) * 4;                              // 33.6 MB
    (void)ws_size; (void)in_sizes; (void)n_in; (void)out_size;

    hipMemsetAsync(seg1, 0x80, (size_t)(NSEG1 + NSEG2) * SEG_U32 * 4, stream);

    {
        int nseg = NSEG1 + NSEG2;                   // 11264 waves
        k_prep<<<(nseg + 3) / 4, 256, 0, stream>>>(mat, seg1, seg2, hdr1, hdr2);
    }
    {
        dim3 g(BATCH / 64, IN_DIM / 64);            // 128 x 16
        k_xt<<<g, 256, 0, stream>>>(x, x_t);
    }
    {
        dim3 g(BATCH / BT, 16);                     // 32 x 16 = 512 blocks
        k_hid<<<g, 1024, 0, stream>>>(x_t, w, seg1, hdr1, hidden_t);
    }
    {
        dim3 g(BATCH / BT, 2, 8);                   // 32 x 2 x 8 = 512 blocks
        k_out<<<g, 1024, 0, stream>>>(x_t, hidden_t, w, seg2, hdr2, partials);
    }
    {
        dim3 g(BATCH / 128, OUT_DIM / 16);          // 64 x 16 = 1024 blocks
        k_sum<<<g, 256, 0, stream>>>(partials, out);
    }
}

// Round 10
// 241.147 us; speedup vs baseline: 1.3716x; 1.3716x over previous
//
#include <hip/hip_runtime.h>
#include <hip/hip_bf16.h>
#include <stdint.h>

// Problem constants
#define BATCH   8192
#define IN_DIM  1024
#define N_HID   2048
#define OUT_DIM 256
#define SRC_DIM 3072

// Tiling
#define C     32                   // source columns per chunk
#define RB    16                   // rows per row-block (= rows per wave)
#define BT    256                  // batch per block (4/lane)
#define S1_CH (IN_DIM / C)         // 32
#define S1_RB (N_HID / RB)         // 128
#define S2_CH (SRC_DIM / C)        // 96
#define S2_RB (OUT_DIM / RB)       // 16
#define NSEG1 (S1_RB * S1_CH)      // 4096
#define NSEG2 (S2_RB * S2_CH)      // 1536
#define ZSLOT 128                  // A-tile zero page (fp16 0x0000 = +0)
#define SEG_U32 160                // segment stride (640 B)
#define ABUF_U32 ((4 * C + 1) * 128)  // 16512 u32 = 64.5 KB A-tile

// Segment format v5 (RB=16, granule-2 overflow):
//   u32[0..7]   plane-0: row r -> u16 at byte 2r (2 slot bytes, pad 0x80)
//   overflow planes p=1..15 at u32 8+9(p-1), stride 9:
//     [0]    = 16-bit row mask (rows with n > 2p)
//     [1..8] = u16 per row: 2 slot bytes for ov idx 2(p-1), 2(p-1)+1
// LESSONS: R1 plane-0 must stay unconditional (vector gating ~70 VALU/slot).
// R4: no long-lived preload arrays (acc scratch spill, 9297us).
// R8/R9 CONFIRMED: occupancy limiter is the UNIFIED VGPR+AGPR file; accs
// live in AGPRs uncounted by VGPR_Count; <=64 TOTAL regs => 32 waves/CU.
// R9: RB=8 got 73% occupancy but acts-recompute x2 ate the gain (+34us).
// R10: FP16 PACKED ACCUMULATION -- acc[16]x4batches as half2 = 32 regs at
// RB=16 (8 row-splits, acts tax back to x8) AND <=64 total regs. A-tile
// fp16 -> slot op = ds_read_b64 + 2 v_pk_add_f16 (~3 VALU vs 7, no unpack).
// absmax tolerance 8.0 >> fp16 acc error (~0.8 worst case). k_hid 2/CU via
// chunk-split (2 groups x 16 chunks, partial fp16 planes summed in k_out).
// VERIFY: occupancy >=70 + VALU-work ~75us. DANGER: WRITE >> 65MB = spill.

#define RFL(x) __builtin_amdgcn_readfirstlane((uint32_t)(x))

typedef _Float16 h2 __attribute__((ext_vector_type(2)));

// ---------------------------------------------------------------------------
__global__ void k_prep(const int* __restrict__ mat,
                       uint32_t* __restrict__ seg1, uint32_t* __restrict__ seg2,
                       uint32_t* __restrict__ hdr1, uint32_t* __restrict__ hdr2) {
    int wid  = (blockIdx.x * blockDim.x + threadIdx.x) >> 6;
    int lane = threadIdx.x & 63;
    if (wid >= NSEG1 + NSEG2) return;

    int row0, col0;
    uint32_t *seg, *hdr;
    if (wid < NSEG1) {
        int rb = wid / S1_CH, ch = wid % S1_CH;
        row0 = rb * RB;          col0 = ch * C;
        seg = seg1 + (size_t)wid * SEG_U32;  hdr = hdr1 + wid;
    } else {
        int s  = wid - NSEG1;
        int rb = s / S2_CH, ch = s % S2_CH;
        row0 = N_HID + rb * RB;  col0 = ch * C;
        seg = seg2 + (size_t)s * SEG_U32;    hdr = hdr2 + s;
    }

    int n = 0;
    if (lane < RB) {
        const int4* m4 = (const int4*)(mat + (size_t)(row0 + lane) * SRC_DIM + col0);
        uint8_t* sb = (uint8_t*)seg;
        #pragma unroll
        for (int cc = 0; cc < 8; cc++) {
            int4 q4 = m4[cc];
            int codes[4] = {q4.x, q4.y, q4.z, q4.w};
            #pragma unroll
            for (int k = 0; k < 4; k++) {
                int code = codes[k];
                if (code != 0) {
                    int c = cc * 4 + k;
                    uint8_t slot = (uint8_t)((code - 1) * C + c);
                    if (n < 2) {
                        sb[2 * lane + n] = slot;           // plane-0 u16
                    } else {
                        int j  = n - 2;                    // overflow index
                        int pl = j >> 1;                   // 0-based ov plane
                        sb[(size_t)(8 + 9 * pl + 1 + (lane >> 1)) * 4
                           + (lane & 1) * 2 + (j & 1)] = slot;
                    }
                    n++;
                }
            }
        }
    }
    int m = n;
    #pragma unroll
    for (int d = 1; d < 64; d <<= 1) m = max(m, __shfl_xor(m, d));
    uint32_t Wv = (m <= 2) ? 1u : 1u + (uint32_t)((m - 1) >> 1);

    for (uint32_t p = 1; p < Wv; p++) {
        unsigned long long b = __ballot(n > (int)(2 * p));
        if (lane == 0) seg[8 + 9 * (p - 1)] = (uint32_t)(b & 0xFFFFu);
    }
    if (lane == 0) *hdr = Wv;
}

// ---------------------------------------------------------------------------
// k_xt: transpose x[8192][1024] -> x_t[1024][8192] (fp32), 64x64 LDS tiles.
// ---------------------------------------------------------------------------
__global__ __launch_bounds__(256) void k_xt(const float* __restrict__ x,
                                            float* __restrict__ x_t) {
    __shared__ float t[64][65];
    const int b0 = blockIdx.x * 64, c0 = blockIdx.y * 64;
    {
        int r  = threadIdx.x >> 4;
        int cq = (threadIdx.x & 15) * 4;
        #pragma unroll
        for (int k = 0; k < 4; k++) {
            int rr = r + 16 * k;
            float4 v = *(const float4*)&x[(size_t)(b0 + rr) * IN_DIM + c0 + cq];
            t[rr][cq + 0] = v.x; t[rr][cq + 1] = v.y;
            t[rr][cq + 2] = v.z; t[rr][cq + 3] = v.w;
        }
    }
    __syncthreads();
    {
        int bq  = (threadIdx.x & 15) * 4;
        int cc0 = threadIdx.x >> 4;
        #pragma unroll
        for (int k = 0; k < 4; k++) {
            int cc = cc0 + 16 * k;
            float4 v;
            v.x = t[bq + 0][cc]; v.y = t[bq + 1][cc];
            v.z = t[bq + 2][cc]; v.w = t[bq + 3][cc];
            *(float4*)&x_t[(size_t)(c0 + cc) * BATCH + b0 + bq] = v;
        }
    }
}

// pack two floats as fp16 pair (v_cvt_pkrtz_f16_f32, 1 instr)
__device__ __forceinline__ uint32_t pkh(float a, float b) {
    auto r = __builtin_amdgcn_cvt_pkrtz(a, b);
    return __builtin_bit_cast(uint32_t, r);
}

__device__ __forceinline__ float rcp_f(float x) { return __builtin_amdgcn_rcpf(x); }

// write 4 activation slots for column c, 4 batches per lane (v pre-scaled by w).
// Values stored as fp16 pairs. Trans budget/elem: 1 v_exp + 2 v_rcp.
__device__ __forceinline__ void write_acts4(uint32_t* As, int c, int lane, float4 v) {
    *(uint2*)&As[(size_t)(0 * C + c) * 128 + 2 * lane] =
        make_uint2(pkh(v.x, v.y), pkh(v.z, v.w));
    *(uint2*)&As[(size_t)(1 * C + c) * 128 + 2 * lane] =
        make_uint2(pkh(fmaxf(v.x, 0.0f), fmaxf(v.y, 0.0f)),
                   pkh(fmaxf(v.z, 0.0f), fmaxf(v.w, 0.0f)));
    float ex = __expf(-v.x), ey = __expf(-v.y);
    float ez = __expf(-v.z), ew = __expf(-v.w);
    float tx = fmaf(2.0f, rcp_f(fmaf(ex, ex, 1.0f)), -1.0f);
    float ty = fmaf(2.0f, rcp_f(fmaf(ey, ey, 1.0f)), -1.0f);
    float tz = fmaf(2.0f, rcp_f(fmaf(ez, ez, 1.0f)), -1.0f);
    float tw = fmaf(2.0f, rcp_f(fmaf(ew, ew, 1.0f)), -1.0f);
    *(uint2*)&As[(size_t)(2 * C + c) * 128 + 2 * lane] =
        make_uint2(pkh(tx, ty), pkh(tz, tw));
    float sx = rcp_f(1.0f + ex), sy = rcp_f(1.0f + ey);
    float sz = rcp_f(1.0f + ez), sw = rcp_f(1.0f + ew);
    *(uint2*)&As[(size_t)(3 * C + c) * 128 + 2 * lane] =
        make_uint2(pkh(sx, sy), pkh(sz, sw));
}

// one slot: ds_read_b64 -> 2 v_pk_add_f16 (4 batches/lane). ~3 VALU total.
#define SLOT_ACC(R, S)                                                         \
    {                                                                          \
        uint2 q_ = *(const uint2*)&As[(size_t)(S) * 128 + 2 * lane];           \
        accA[R] += __builtin_bit_cast(h2, q_.x);                               \
        accB[R] += __builtin_bit_cast(h2, q_.y);                               \
    }

// v5: plane-0 unconditional (pads hit zero page); overflow planes granule-2,
// scalar-gated, words loaded INSIDE the guard (R4 lesson).
#define EDGE_PLANES(SEGBASE, WVAL)                                             \
    {                                                                          \
        const uint32_t* sp_ = (SEGBASE);                                       \
        _Pragma("unroll")                                                      \
        for (int i = 0; i < 8; i++) {                                          \
            uint32_t g = RFL(sp_[i]);                                          \
            SLOT_ACC(2 * i,     g & 255u)                                      \
            SLOT_ACC(2 * i,     (g >> 8) & 255u)                               \
            SLOT_ACC(2 * i + 1, (g >> 16) & 255u)                              \
            SLOT_ACC(2 * i + 1, g >> 24)                                       \
        }                                                                      \
        _Pragma("unroll 1")                                                    \
        for (uint32_t p = 1; p < (WVAL); p++) {                                \
            const uint32_t* pp_ = sp_ + 8 + 9 * (p - 1);                       \
            uint32_t mask = RFL(pp_[0]);                                       \
            _Pragma("unroll")                                                  \
            for (int r = 0; r < RB; r++) {                                     \
                if (mask & (1u << r)) {                                        \
                    uint32_t h_ = RFL(pp_[1 + (r >> 1)]);                      \
                    uint32_t u_ = (r & 1) ? (h_ >> 16) : h_;                   \
                    SLOT_ACC(r, u_ & 255u)                                     \
                    SLOT_ACC(r, (u_ >> 8) & 255u)                              \
                }                                                              \
            }                                                                  \
        }                                                                      \
    }

// ---------------------------------------------------------------------------
// Stage 1: 16 waves x 16 rows = 256 rows; 256 batches; 16 chunks per block.
// Grid (32 tiles, 8 row splits, 2 chunk groups) = 512 blocks = 2/CU
// (acc fp16-packed: 32 regs; total <=64 => 32 waves/CU; LDS 2x66KB).
// Output: fp16 partial hidden plane per chunk-group (summed in k_out loads).
// ---------------------------------------------------------------------------
__global__ __launch_bounds__(1024, 8) void k_hid(const float* __restrict__ x_t,
                                                 const float* __restrict__ wp,
                                                 const uint32_t* __restrict__ seg1,
                                                 const uint32_t* __restrict__ hdr1,
                                                 uint16_t* __restrict__ hidden_t) {
    __shared__ uint32_t As[ABUF_U32];           // 64.5 KB

    const float w  = wp[0];
    const int tile = blockIdx.x;                // 0..31
    const int cgh  = blockIdx.z;                // 0..1 (chunk group)
    const int lane = threadIdx.x & 63;
    const int wv   = __builtin_amdgcn_readfirstlane(threadIdx.x >> 6); // 0..15
    const int rb   = blockIdx.y * 16 + wv;      // row-block 0..127
    const int b0   = tile * BT;
    const int c0   = cgh * (S1_CH / 2);         // first chunk of group

    if (threadIdx.x < 128) As[ZSLOT * 128 + threadIdx.x] = 0u;

    h2 accA[RB], accB[RB];
    const h2 hz = {(_Float16)0.0f, (_Float16)0.0f};
    #pragma unroll
    for (int r = 0; r < RB; r++) { accA[r] = hz; accB[r] = hz; }

    // prefetch first chunk: each wave owns 2 columns, 4 batches/lane
    float4 v[2];
    #pragma unroll
    for (int j = 0; j < 2; j++) {
        int gcol = c0 * C + wv * 2 + j;
        const float2* xp = (const float2*)&x_t[(size_t)gcol * BATCH + b0];
        float2 u0 = xp[lane], u1 = xp[64 + lane];
        v[j] = make_float4(w * u0.x, w * u0.y, w * u1.x, w * u1.y);
    }

    #pragma unroll 1
    for (int cj = 0; cj < S1_CH / 2; cj++) {
        int ch = c0 + cj;
        __syncthreads();                        // edge(ch-1) done (WAR)
        write_acts4(As, wv * 2 + 0, lane, v[0]);
        write_acts4(As, wv * 2 + 1, lane, v[1]);
        __syncthreads();                        // acts visible
        if (cj + 1 < S1_CH / 2) {               // prefetch next chunk
            #pragma unroll
            for (int j = 0; j < 2; j++) {
                int gcol = (ch + 1) * C + wv * 2 + j;
                const float2* xp = (const float2*)&x_t[(size_t)gcol * BATCH + b0];
                float2 u0 = xp[lane], u1 = xp[64 + lane];
                v[j] = make_float4(w * u0.x, w * u0.y, w * u1.x, w * u1.y);
            }
        }
        int sidx = rb * S1_CH + ch;
        uint32_t W = RFL(hdr1[sidx]);
        EDGE_PLANES(seg1 + (size_t)sidx * SEG_U32, W)
    }

    uint16_t* hout = hidden_t + (size_t)cgh * N_HID * BATCH;
    const int row0 = rb * RB;
    #pragma unroll
    for (int r = 0; r < RB; r++) {              // acc is already fp16-packed
        *(uint32_t*)&hout[(size_t)(row0 + r) * BATCH + b0 + 2 * lane] =
            __builtin_bit_cast(uint32_t, accA[r]);
        *(uint32_t*)&hout[(size_t)(row0 + r) * BATCH + b0 + 128 + 2 * lane] =
            __builtin_bit_cast(uint32_t, accB[r]);
    }
}

// source loader for stage 2: x_t fp32, or SUM of 2 fp16 partial hidden planes
__device__ __forceinline__ float4 load_src4(const float* __restrict__ x_t,
                                            const uint16_t* __restrict__ hidden_t,
                                            int gcol, int b0, int lane, float w) {
    if (gcol < IN_DIM) {
        const float2* xp = (const float2*)&x_t[(size_t)gcol * BATCH + b0];
        float2 u0 = xp[lane], u1 = xp[64 + lane];
        return make_float4(w * u0.x, w * u0.y, w * u1.x, w * u1.y);
    } else {
        const uint16_t* hp = hidden_t + (size_t)(gcol - IN_DIM) * BATCH + b0;
        const uint16_t* hq = hp + (size_t)N_HID * BATCH;   // partial plane 1
        uint32_t a0 = *(const uint32_t*)&hp[2 * lane];
        uint32_t a1 = *(const uint32_t*)&hp[128 + 2 * lane];
        uint32_t c0 = *(const uint32_t*)&hq[2 * lane];
        uint32_t c1 = *(const uint32_t*)&hq[128 + 2 * lane];
        h2 s0 = __builtin_bit_cast(h2, a0) + __builtin_bit_cast(h2, c0);
        h2 s1 = __builtin_bit_cast(h2, a1) + __builtin_bit_cast(h2, c1);
        return make_float4(w * (float)s0.x, w * (float)s0.y,
                           w * (float)s1.x, w * (float)s1.y);
    }
}

// ---------------------------------------------------------------------------
// Stage 2: 16 waves x 16 rows = ALL 256 out rows; 256 batches per block.
// Grid (32 tiles, 8 chunk groups of 12) = 256 blocks (1/CU max possible --
// so launch_bounds(1024,4) grants 128-reg budget, zero spill risk).
// Partials fp16-packed [cg][row][b/2].
// ---------------------------------------------------------------------------
__global__ __launch_bounds__(1024, 4) void k_out(const float* __restrict__ x_t,
                                                 const uint16_t* __restrict__ hidden_t,
                                                 const float* __restrict__ wp,
                                                 const uint32_t* __restrict__ seg2,
                                                 const uint32_t* __restrict__ hdr2,
                                                 uint32_t* __restrict__ partials) {
    __shared__ uint32_t As[ABUF_U32];

    const float w  = wp[0];
    const int tile = blockIdx.x;                // 0..31
    const int cg   = blockIdx.y;                // 0..7
    const int lane = threadIdx.x & 63;
    const int wv   = __builtin_amdgcn_readfirstlane(threadIdx.x >> 6); // 0..15
    const int b0   = tile * BT;

    if (threadIdx.x < 128) As[ZSLOT * 128 + threadIdx.x] = 0u;

    h2 accA[RB], accB[RB];
    const h2 hz = {(_Float16)0.0f, (_Float16)0.0f};
    #pragma unroll
    for (int r = 0; r < RB; r++) { accA[r] = hz; accB[r] = hz; }

    float4 v[2];
    #pragma unroll
    for (int j = 0; j < 2; j++)
        v[j] = load_src4(x_t, hidden_t, (cg * 12) * C + wv * 2 + j, b0, lane, w);

    #pragma unroll 1
    for (int cj = 0; cj < 12; cj++) {
        int ch = cg * 12 + cj;
        __syncthreads();
        write_acts4(As, wv * 2 + 0, lane, v[0]);
        write_acts4(As, wv * 2 + 1, lane, v[1]);
        __syncthreads();
        if (cj + 1 < 12) {
            #pragma unroll
            for (int j = 0; j < 2; j++)
                v[j] = load_src4(x_t, hidden_t, (ch + 1) * C + wv * 2 + j, b0, lane, w);
        }
        int sidx = wv * S2_CH + ch;              // wv = row-block 0..15
        uint32_t W = RFL(hdr2[sidx]);
        EDGE_PLANES(seg2 + (size_t)sidx * SEG_U32, W)
    }

    #pragma unroll
    for (int r = 0; r < RB; r++) {
        size_t base = ((size_t)cg * OUT_DIM + wv * RB + r) * (BATCH / 2) + (b0 >> 1);
        partials[base + lane]      = __builtin_bit_cast(uint32_t, accA[r]);
        partials[base + 64 + lane] = __builtin_bit_cast(uint32_t, accB[r]);
    }
}

// ---------------------------------------------------------------------------
// k_sum: reduce 8 fp16-packed partial planes + transpose -> out[b][r].
// Block: 128 batches x 16 rows. Grid (64, 16).
// ---------------------------------------------------------------------------
__global__ __launch_bounds__(256) void k_sum(const uint32_t* __restrict__ partials,
                                             float* __restrict__ out) {
    __shared__ float t[16][130];
    const int b0 = blockIdx.x * 128, r0 = blockIdx.y * 16;
    const int lane = threadIdx.x & 63;
    const int g4   = threadIdx.x >> 6;          // 0..3

    #pragma unroll
    for (int k = 0; k < 4; k++) {
        int rr = g4 * 4 + k;
        float sx = 0.0f, sy = 0.0f;
        #pragma unroll
        for (int cg = 0; cg < 8; cg++) {
            uint32_t q = partials[((size_t)cg * OUT_DIM + r0 + rr) * (BATCH / 2)
                                  + (b0 >> 1) + lane];
            h2 h = __builtin_bit_cast(h2, q);
            sx += (float)h.x;
            sy += (float)h.y;
        }
        t[rr][2 * lane]     = sx;
        t[rr][2 * lane + 1] = sy;
    }
    __syncthreads();
    #pragma unroll
    for (int k = 0; k < 2; k++) {
        int idx = threadIdx.x + 256 * k;        // 0..511
        int bb = idx >> 2, rq = idx & 3;
        float4 v;
        v.x = t[rq * 4 + 0][bb];
        v.y = t[rq * 4 + 1][bb];
        v.z = t[rq * 4 + 2][bb];
        v.w = t[rq * 4 + 3][bb];
        *(float4*)&out[(size_t)(b0 + bb) * OUT_DIM + r0 + rq * 4] = v;
    }
}

// ---------------------------------------------------------------------------
extern "C" void kernel_launch(void* const* d_in, const int* in_sizes, int n_in,
                              void* d_out, int out_size, void* d_ws, size_t ws_size,
                              hipStream_t stream) {
    const float* x   = (const float*)d_in[0];
    const float* w   = (const float*)d_in[1];
    const int*   mat = (const int*)d_in[2];
    float* out = (float*)d_out;

    uint8_t* ws = (uint8_t*)d_ws;
    size_t off = 0;
    uint16_t* hidden_t = (uint16_t*)(ws + off);
    off += (size_t)2 * BATCH * N_HID * 2;                                      // 67.1 MB (2 fp16 planes)
    float* x_t = (float*)(ws + off);        off += (size_t)IN_DIM * BATCH * 4; // 33.6 MB
    uint32_t* seg1 = (uint32_t*)(ws + off); off += (size_t)NSEG1 * SEG_U32 * 4;//  2.62 MB
    uint32_t* seg2 = (uint32_t*)(ws + off); off += (size_t)NSEG2 * SEG_U32 * 4;//  0.98 MB
    uint32_t* hdr1 = (uint32_t*)(ws + off); off += (size_t)NSEG1 * 4;
    uint32_t* hdr2 = (uint32_t*)(ws + off); off += (size_t)NSEG2 * 4;
    uint32_t* partials = (uint32_t*)(ws + off);
    off += (size_t)8 * OUT_DIM * (BATCH / 2) * 4;                              // 33.6 MB
    (void)ws_size; (void)in_sizes; (void)n_in; (void)out_size;

    hipMemsetAsync(seg1, 0x80, (size_t)(NSEG1 + NSEG2) * SEG_U32 * 4, stream);

    {
        int nseg = NSEG1 + NSEG2;                   // 5632 waves
        k_prep<<<(nseg + 3) / 4, 256, 0, stream>>>(mat, seg1, seg2, hdr1, hdr2);
    }
    {
        dim3 g(BATCH / 64, IN_DIM / 64);            // 128 x 16
        k_xt<<<g, 256, 0, stream>>>(x, x_t);
    }
    {
        dim3 g(BATCH / BT, 8, 2);                   // 32 x 8 x 2 = 512 blocks
        k_hid<<<g, 1024, 0, stream>>>(x_t, w, seg1, hdr1, hidden_t);
    }
    {
        dim3 g(BATCH / BT, 8);                      // 32 x 8 = 256 blocks
        k_out<<<g, 1024, 0, stream>>>(x_t, hidden_t, w, seg2, hdr2, partials);
    }
    {
        dim3 g(BATCH / 128, OUT_DIM / 16);          // 64 x 16 = 1024 blocks
        k_sum<<<g, 256, 0, stream>>>(partials, out);
    }
}

// Round 11
// 238.725 us; speedup vs baseline: 1.3855x; 1.0101x over previous
//
#include <hip/hip_runtime.h>
#include <hip/hip_bf16.h>
#include <stdint.h>

// Problem constants
#define BATCH   8192
#define IN_DIM  1024
#define N_HID   2048
#define OUT_DIM 256
#define SRC_DIM 3072

// Tiling
#define C     32                   // source columns per chunk
#define RB    16                   // rows per row-block (= rows per wave)
#define BT    256                  // batch per block (4/lane)
#define S1_CH (IN_DIM / C)         // 32
#define S1_RB (N_HID / RB)         // 128
#define S2_CH (SRC_DIM / C)        // 96
#define S2_RB (OUT_DIM / RB)       // 16
#define NSEG1 (S1_RB * S1_CH)      // 4096
#define NSEG2 (S2_RB * S2_CH)      // 1536
#define NCG2  16                   // k_out chunk groups (6 chunks each)
#define ZSLOT 128                  // A-tile zero page (fp16 0x0000 = +0)
#define SEG_U32 160                // segment stride (640 B)
#define ABUF_U32 ((4 * C + 1) * 128)  // 16512 u32 = 64.5 KB A-tile

// Segment format v5 (RB=16, granule-2 overflow):
//   u32[0..7]   plane-0: row r -> u16 at byte 2r (2 slot bytes, pad 0x80)
//   overflow planes p=1..15 at u32 8+9(p-1), stride 9:
//     [0]    = 16-bit row mask (rows with n > 2p)
//     [1..8] = u16 per row: 2 slot bytes for ov idx 2(p-1), 2(p-1)+1
// LESSONS: R1 plane-0 unconditional (vector gating ~70 VALU/slot).
// R4: no long-lived preload arrays (acc scratch spill, 9297us).
// R8/R9/R10 CONFIRMED: occupancy limiter = UNIFIED VGPR+AGPR file; accs in
// AGPRs uncounted by VGPR_Count; <=64 TOTAL regs => 32 waves/CU.
// R10 (241us): fp16-packed acc = 32 regs at RB=16 -> k_hid 2 blocks/CU,
// occupancy 70%, 155->87us. k_out left at 1 block/CU: ~110us, wall/work 1.6.
// R11: same recipe for k_out -- cg 8->16 (6 chunks/block, ZERO acts
// duplication: chunk acts were already computed once per (tile,chunk)),
// 512 blocks = 2/CU, launch_bounds(1024,8). Partials 16 fp16 planes.
// VERIFY: k_out occupancy ~70. DANGER: k_out WRITE >> 33MB = spill.

#define RFL(x) __builtin_amdgcn_readfirstlane((uint32_t)(x))

typedef _Float16 h2 __attribute__((ext_vector_type(2)));

// ---------------------------------------------------------------------------
__global__ void k_prep(const int* __restrict__ mat,
                       uint32_t* __restrict__ seg1, uint32_t* __restrict__ seg2,
                       uint32_t* __restrict__ hdr1, uint32_t* __restrict__ hdr2) {
    int wid  = (blockIdx.x * blockDim.x + threadIdx.x) >> 6;
    int lane = threadIdx.x & 63;
    if (wid >= NSEG1 + NSEG2) return;

    int row0, col0;
    uint32_t *seg, *hdr;
    if (wid < NSEG1) {
        int rb = wid / S1_CH, ch = wid % S1_CH;
        row0 = rb * RB;          col0 = ch * C;
        seg = seg1 + (size_t)wid * SEG_U32;  hdr = hdr1 + wid;
    } else {
        int s  = wid - NSEG1;
        int rb = s / S2_CH, ch = s % S2_CH;
        row0 = N_HID + rb * RB;  col0 = ch * C;
        seg = seg2 + (size_t)s * SEG_U32;    hdr = hdr2 + s;
    }

    int n = 0;
    if (lane < RB) {
        const int4* m4 = (const int4*)(mat + (size_t)(row0 + lane) * SRC_DIM + col0);
        uint8_t* sb = (uint8_t*)seg;
        #pragma unroll
        for (int cc = 0; cc < 8; cc++) {
            int4 q4 = m4[cc];
            int codes[4] = {q4.x, q4.y, q4.z, q4.w};
            #pragma unroll
            for (int k = 0; k < 4; k++) {
                int code = codes[k];
                if (code != 0) {
                    int c = cc * 4 + k;
                    uint8_t slot = (uint8_t)((code - 1) * C + c);
                    if (n < 2) {
                        sb[2 * lane + n] = slot;           // plane-0 u16
                    } else {
                        int j  = n - 2;                    // overflow index
                        int pl = j >> 1;                   // 0-based ov plane
                        sb[(size_t)(8 + 9 * pl + 1 + (lane >> 1)) * 4
                           + (lane & 1) * 2 + (j & 1)] = slot;
                    }
                    n++;
                }
            }
        }
    }
    int m = n;
    #pragma unroll
    for (int d = 1; d < 64; d <<= 1) m = max(m, __shfl_xor(m, d));
    uint32_t Wv = (m <= 2) ? 1u : 1u + (uint32_t)((m - 1) >> 1);

    for (uint32_t p = 1; p < Wv; p++) {
        unsigned long long b = __ballot(n > (int)(2 * p));
        if (lane == 0) seg[8 + 9 * (p - 1)] = (uint32_t)(b & 0xFFFFu);
    }
    if (lane == 0) *hdr = Wv;
}

// ---------------------------------------------------------------------------
// k_xt: transpose x[8192][1024] -> x_t[1024][8192] (fp32), 64x64 LDS tiles.
// ---------------------------------------------------------------------------
__global__ __launch_bounds__(256) void k_xt(const float* __restrict__ x,
                                            float* __restrict__ x_t) {
    __shared__ float t[64][65];
    const int b0 = blockIdx.x * 64, c0 = blockIdx.y * 64;
    {
        int r  = threadIdx.x >> 4;
        int cq = (threadIdx.x & 15) * 4;
        #pragma unroll
        for (int k = 0; k < 4; k++) {
            int rr = r + 16 * k;
            float4 v = *(const float4*)&x[(size_t)(b0 + rr) * IN_DIM + c0 + cq];
            t[rr][cq + 0] = v.x; t[rr][cq + 1] = v.y;
            t[rr][cq + 2] = v.z; t[rr][cq + 3] = v.w;
        }
    }
    __syncthreads();
    {
        int bq  = (threadIdx.x & 15) * 4;
        int cc0 = threadIdx.x >> 4;
        #pragma unroll
        for (int k = 0; k < 4; k++) {
            int cc = cc0 + 16 * k;
            float4 v;
            v.x = t[bq + 0][cc]; v.y = t[bq + 1][cc];
            v.z = t[bq + 2][cc]; v.w = t[bq + 3][cc];
            *(float4*)&x_t[(size_t)(c0 + cc) * BATCH + b0 + bq] = v;
        }
    }
}

// pack two floats as fp16 pair (v_cvt_pkrtz_f16_f32, 1 instr)
__device__ __forceinline__ uint32_t pkh(float a, float b) {
    auto r = __builtin_amdgcn_cvt_pkrtz(a, b);
    return __builtin_bit_cast(uint32_t, r);
}

__device__ __forceinline__ float rcp_f(float x) { return __builtin_amdgcn_rcpf(x); }

// write 4 activation slots for column c, 4 batches per lane (v pre-scaled by w).
// Values stored as fp16 pairs. Trans budget/elem: 1 v_exp + 2 v_rcp.
__device__ __forceinline__ void write_acts4(uint32_t* As, int c, int lane, float4 v) {
    *(uint2*)&As[(size_t)(0 * C + c) * 128 + 2 * lane] =
        make_uint2(pkh(v.x, v.y), pkh(v.z, v.w));
    *(uint2*)&As[(size_t)(1 * C + c) * 128 + 2 * lane] =
        make_uint2(pkh(fmaxf(v.x, 0.0f), fmaxf(v.y, 0.0f)),
                   pkh(fmaxf(v.z, 0.0f), fmaxf(v.w, 0.0f)));
    float ex = __expf(-v.x), ey = __expf(-v.y);
    float ez = __expf(-v.z), ew = __expf(-v.w);
    float tx = fmaf(2.0f, rcp_f(fmaf(ex, ex, 1.0f)), -1.0f);
    float ty = fmaf(2.0f, rcp_f(fmaf(ey, ey, 1.0f)), -1.0f);
    float tz = fmaf(2.0f, rcp_f(fmaf(ez, ez, 1.0f)), -1.0f);
    float tw = fmaf(2.0f, rcp_f(fmaf(ew, ew, 1.0f)), -1.0f);
    *(uint2*)&As[(size_t)(2 * C + c) * 128 + 2 * lane] =
        make_uint2(pkh(tx, ty), pkh(tz, tw));
    float sx = rcp_f(1.0f + ex), sy = rcp_f(1.0f + ey);
    float sz = rcp_f(1.0f + ez), sw = rcp_f(1.0f + ew);
    *(uint2*)&As[(size_t)(3 * C + c) * 128 + 2 * lane] =
        make_uint2(pkh(sx, sy), pkh(sz, sw));
}

// one slot: ds_read_b64 -> 2 v_pk_add_f16 (4 batches/lane). ~3 VALU total.
#define SLOT_ACC(R, S)                                                         \
    {                                                                          \
        uint2 q_ = *(const uint2*)&As[(size_t)(S) * 128 + 2 * lane];           \
        accA[R] += __builtin_bit_cast(h2, q_.x);                               \
        accB[R] += __builtin_bit_cast(h2, q_.y);                               \
    }

// v5: plane-0 unconditional (pads hit zero page); overflow planes granule-2,
// scalar-gated, words loaded INSIDE the guard (R4 lesson).
#define EDGE_PLANES(SEGBASE, WVAL)                                             \
    {                                                                          \
        const uint32_t* sp_ = (SEGBASE);                                       \
        _Pragma("unroll")                                                      \
        for (int i = 0; i < 8; i++) {                                          \
            uint32_t g = RFL(sp_[i]);                                          \
            SLOT_ACC(2 * i,     g & 255u)                                      \
            SLOT_ACC(2 * i,     (g >> 8) & 255u)                               \
            SLOT_ACC(2 * i + 1, (g >> 16) & 255u)                              \
            SLOT_ACC(2 * i + 1, g >> 24)                                       \
        }                                                                      \
        _Pragma("unroll 1")                                                    \
        for (uint32_t p = 1; p < (WVAL); p++) {                                \
            const uint32_t* pp_ = sp_ + 8 + 9 * (p - 1);                       \
            uint32_t mask = RFL(pp_[0]);                                       \
            _Pragma("unroll")                                                  \
            for (int r = 0; r < RB; r++) {                                     \
                if (mask & (1u << r)) {                                        \
                    uint32_t h_ = RFL(pp_[1 + (r >> 1)]);                      \
                    uint32_t u_ = (r & 1) ? (h_ >> 16) : h_;                   \
                    SLOT_ACC(r, u_ & 255u)                                     \
                    SLOT_ACC(r, (u_ >> 8) & 255u)                              \
                }                                                              \
            }                                                                  \
        }                                                                      \
    }

// ---------------------------------------------------------------------------
// Stage 1: 16 waves x 16 rows = 256 rows; 256 batches; 16 chunks per block.
// Grid (32 tiles, 8 row splits, 2 chunk groups) = 512 blocks = 2/CU
// (acc fp16-packed: 32 regs; total <=64 => 32 waves/CU; LDS 2x66KB).
// Output: fp16 partial hidden plane per chunk-group (summed in k_out loads).
// ---------------------------------------------------------------------------
__global__ __launch_bounds__(1024, 8) void k_hid(const float* __restrict__ x_t,
                                                 const float* __restrict__ wp,
                                                 const uint32_t* __restrict__ seg1,
                                                 const uint32_t* __restrict__ hdr1,
                                                 uint16_t* __restrict__ hidden_t) {
    __shared__ uint32_t As[ABUF_U32];           // 64.5 KB

    const float w  = wp[0];
    const int tile = blockIdx.x;                // 0..31
    const int cgh  = blockIdx.z;                // 0..1 (chunk group)
    const int lane = threadIdx.x & 63;
    const int wv   = __builtin_amdgcn_readfirstlane(threadIdx.x >> 6); // 0..15
    const int rb   = blockIdx.y * 16 + wv;      // row-block 0..127
    const int b0   = tile * BT;
    const int c0   = cgh * (S1_CH / 2);         // first chunk of group

    if (threadIdx.x < 128) As[ZSLOT * 128 + threadIdx.x] = 0u;

    h2 accA[RB], accB[RB];
    const h2 hz = {(_Float16)0.0f, (_Float16)0.0f};
    #pragma unroll
    for (int r = 0; r < RB; r++) { accA[r] = hz; accB[r] = hz; }

    // prefetch first chunk: each wave owns 2 columns, 4 batches/lane
    float4 v[2];
    #pragma unroll
    for (int j = 0; j < 2; j++) {
        int gcol = c0 * C + wv * 2 + j;
        const float2* xp = (const float2*)&x_t[(size_t)gcol * BATCH + b0];
        float2 u0 = xp[lane], u1 = xp[64 + lane];
        v[j] = make_float4(w * u0.x, w * u0.y, w * u1.x, w * u1.y);
    }

    #pragma unroll 1
    for (int cj = 0; cj < S1_CH / 2; cj++) {
        int ch = c0 + cj;
        __syncthreads();                        // edge(ch-1) done (WAR)
        write_acts4(As, wv * 2 + 0, lane, v[0]);
        write_acts4(As, wv * 2 + 1, lane, v[1]);
        __syncthreads();                        // acts visible
        if (cj + 1 < S1_CH / 2) {               // prefetch next chunk
            #pragma unroll
            for (int j = 0; j < 2; j++) {
                int gcol = (ch + 1) * C + wv * 2 + j;
                const float2* xp = (const float2*)&x_t[(size_t)gcol * BATCH + b0];
                float2 u0 = xp[lane], u1 = xp[64 + lane];
                v[j] = make_float4(w * u0.x, w * u0.y, w * u1.x, w * u1.y);
            }
        }
        int sidx = rb * S1_CH + ch;
        uint32_t W = RFL(hdr1[sidx]);
        EDGE_PLANES(seg1 + (size_t)sidx * SEG_U32, W)
    }

    uint16_t* hout = hidden_t + (size_t)cgh * N_HID * BATCH;
    const int row0 = rb * RB;
    #pragma unroll
    for (int r = 0; r < RB; r++) {              // acc is already fp16-packed
        *(uint32_t*)&hout[(size_t)(row0 + r) * BATCH + b0 + 2 * lane] =
            __builtin_bit_cast(uint32_t, accA[r]);
        *(uint32_t*)&hout[(size_t)(row0 + r) * BATCH + b0 + 128 + 2 * lane] =
            __builtin_bit_cast(uint32_t, accB[r]);
    }
}

// source loader for stage 2: x_t fp32, or SUM of 2 fp16 partial hidden planes
__device__ __forceinline__ float4 load_src4(const float* __restrict__ x_t,
                                            const uint16_t* __restrict__ hidden_t,
                                            int gcol, int b0, int lane, float w) {
    if (gcol < IN_DIM) {
        const float2* xp = (const float2*)&x_t[(size_t)gcol * BATCH + b0];
        float2 u0 = xp[lane], u1 = xp[64 + lane];
        return make_float4(w * u0.x, w * u0.y, w * u1.x, w * u1.y);
    } else {
        const uint16_t* hp = hidden_t + (size_t)(gcol - IN_DIM) * BATCH + b0;
        const uint16_t* hq = hp + (size_t)N_HID * BATCH;   // partial plane 1
        uint32_t a0 = *(const uint32_t*)&hp[2 * lane];
        uint32_t a1 = *(const uint32_t*)&hp[128 + 2 * lane];
        uint32_t c0 = *(const uint32_t*)&hq[2 * lane];
        uint32_t c1 = *(const uint32_t*)&hq[128 + 2 * lane];
        h2 s0 = __builtin_bit_cast(h2, a0) + __builtin_bit_cast(h2, c0);
        h2 s1 = __builtin_bit_cast(h2, a1) + __builtin_bit_cast(h2, c1);
        return make_float4(w * (float)s0.x, w * (float)s0.y,
                           w * (float)s1.x, w * (float)s1.y);
    }
}

// ---------------------------------------------------------------------------
// Stage 2: 16 waves x 16 rows = ALL 256 out rows; 256 batches per block.
// Grid (32 tiles, 16 chunk groups of 6) = 512 blocks = 2/CU (R11: same
// occupancy recipe as k_hid; chunk-split has ZERO acts duplication).
// Partials fp16-packed [cg16][row][b/2].
// ---------------------------------------------------------------------------
__global__ __launch_bounds__(1024, 8) void k_out(const float* __restrict__ x_t,
                                                 const uint16_t* __restrict__ hidden_t,
                                                 const float* __restrict__ wp,
                                                 const uint32_t* __restrict__ seg2,
                                                 const uint32_t* __restrict__ hdr2,
                                                 uint32_t* __restrict__ partials) {
    __shared__ uint32_t As[ABUF_U32];

    const float w  = wp[0];
    const int tile = blockIdx.x;                // 0..31
    const int cg   = blockIdx.y;                // 0..15
    const int lane = threadIdx.x & 63;
    const int wv   = __builtin_amdgcn_readfirstlane(threadIdx.x >> 6); // 0..15
    const int b0   = tile * BT;
    const int nch  = S2_CH / NCG2;              // 6 chunks per block

    if (threadIdx.x < 128) As[ZSLOT * 128 + threadIdx.x] = 0u;

    h2 accA[RB], accB[RB];
    const h2 hz = {(_Float16)0.0f, (_Float16)0.0f};
    #pragma unroll
    for (int r = 0; r < RB; r++) { accA[r] = hz; accB[r] = hz; }

    float4 v[2];
    #pragma unroll
    for (int j = 0; j < 2; j++)
        v[j] = load_src4(x_t, hidden_t, (cg * nch) * C + wv * 2 + j, b0, lane, w);

    #pragma unroll 1
    for (int cj = 0; cj < nch; cj++) {
        int ch = cg * nch + cj;
        __syncthreads();
        write_acts4(As, wv * 2 + 0, lane, v[0]);
        write_acts4(As, wv * 2 + 1, lane, v[1]);
        __syncthreads();
        if (cj + 1 < nch) {
            #pragma unroll
            for (int j = 0; j < 2; j++)
                v[j] = load_src4(x_t, hidden_t, (ch + 1) * C + wv * 2 + j, b0, lane, w);
        }
        int sidx = wv * S2_CH + ch;              // wv = row-block 0..15
        uint32_t W = RFL(hdr2[sidx]);
        EDGE_PLANES(seg2 + (size_t)sidx * SEG_U32, W)
    }

    #pragma unroll
    for (int r = 0; r < RB; r++) {
        size_t base = ((size_t)cg * OUT_DIM + wv * RB + r) * (BATCH / 2) + (b0 >> 1);
        partials[base + lane]      = __builtin_bit_cast(uint32_t, accA[r]);
        partials[base + 64 + lane] = __builtin_bit_cast(uint32_t, accB[r]);
    }
}

// ---------------------------------------------------------------------------
// k_sum: reduce 16 fp16-packed partial planes + transpose -> out[b][r].
// Block: 128 batches x 16 rows. Grid (64, 16).
// ---------------------------------------------------------------------------
__global__ __launch_bounds__(256) void k_sum(const uint32_t* __restrict__ partials,
                                             float* __restrict__ out) {
    __shared__ float t[16][130];
    const int b0 = blockIdx.x * 128, r0 = blockIdx.y * 16;
    const int lane = threadIdx.x & 63;
    const int g4   = threadIdx.x >> 6;          // 0..3

    #pragma unroll
    for (int k = 0; k < 4; k++) {
        int rr = g4 * 4 + k;
        float sx = 0.0f, sy = 0.0f;
        #pragma unroll
        for (int cg = 0; cg < NCG2; cg++) {
            uint32_t q = partials[((size_t)cg * OUT_DIM + r0 + rr) * (BATCH / 2)
                                  + (b0 >> 1) + lane];
            h2 h = __builtin_bit_cast(h2, q);
            sx += (float)h.x;
            sy += (float)h.y;
        }
        t[rr][2 * lane]     = sx;
        t[rr][2 * lane + 1] = sy;
    }
    __syncthreads();
    #pragma unroll
    for (int k = 0; k < 2; k++) {
        int idx = threadIdx.x + 256 * k;        // 0..511
        int bb = idx >> 2, rq = idx & 3;
        float4 v;
        v.x = t[rq * 4 + 0][bb];
        v.y = t[rq * 4 + 1][bb];
        v.z = t[rq * 4 + 2][bb];
        v.w = t[rq * 4 + 3][bb];
        *(float4*)&out[(size_t)(b0 + bb) * OUT_DIM + r0 + rq * 4] = v;
    }
}

// ---------------------------------------------------------------------------
extern "C" void kernel_launch(void* const* d_in, const int* in_sizes, int n_in,
                              void* d_out, int out_size, void* d_ws, size_t ws_size,
                              hipStream_t stream) {
    const float* x   = (const float*)d_in[0];
    const float* w   = (const float*)d_in[1];
    const int*   mat = (const int*)d_in[2];
    float* out = (float*)d_out;

    uint8_t* ws = (uint8_t*)d_ws;
    size_t off = 0;
    uint16_t* hidden_t = (uint16_t*)(ws + off);
    off += (size_t)2 * BATCH * N_HID * 2;                                      // 67.1 MB (2 fp16 planes)
    float* x_t = (float*)(ws + off);        off += (size_t)IN_DIM * BATCH * 4; // 33.6 MB
    uint32_t* seg1 = (uint32_t*)(ws + off); off += (size_t)NSEG1 * SEG_U32 * 4;//  2.62 MB
    uint32_t* seg2 = (uint32_t*)(ws + off); off += (size_t)NSEG2 * SEG_U32 * 4;//  0.98 MB
    uint32_t* hdr1 = (uint32_t*)(ws + off); off += (size_t)NSEG1 * 4;
    uint32_t* hdr2 = (uint32_t*)(ws + off); off += (size_t)NSEG2 * 4;
    uint32_t* partials = (uint32_t*)(ws + off);
    off += (size_t)NCG2 * OUT_DIM * (BATCH / 2) * 4;                           // 67.1 MB
    (void)ws_size; (void)in_sizes; (void)n_in; (void)out_size;

    hipMemsetAsync(seg1, 0x80, (size_t)(NSEG1 + NSEG2) * SEG_U32 * 4, stream);

    {
        int nseg = NSEG1 + NSEG2;                   // 5632 waves
        k_prep<<<(nseg + 3) / 4, 256, 0, stream>>>(mat, seg1, seg2, hdr1, hdr2);
    }
    {
        dim3 g(BATCH / 64, IN_DIM / 64);            // 128 x 16
        k_xt<<<g, 256, 0, stream>>>(x, x_t);
    }
    {
        dim3 g(BATCH / BT, 8, 2);                   // 32 x 8 x 2 = 512 blocks
        k_hid<<<g, 1024, 0, stream>>>(x_t, w, seg1, hdr1, hidden_t);
    }
    {
        dim3 g(BATCH / BT, NCG2);                   // 32 x 16 = 512 blocks
        k_out<<<g, 1024, 0, stream>>>(x_t, hidden_t, w, seg2, hdr2, partials);
    }
    {
        dim3 g(BATCH / 128, OUT_DIM / 16);          // 64 x 16 = 1024 blocks
        k_sum<<<g, 256, 0, stream>>>(partials, out);
    }
}

// Round 12
// 235.790 us; speedup vs baseline: 1.4027x; 1.0124x over previous
//
#include <hip/hip_runtime.h>
#include <hip/hip_bf16.h>
#include <stdint.h>

// Problem constants
#define BATCH   8192
#define IN_DIM  1024
#define N_HID   2048
#define OUT_DIM 256
#define SRC_DIM 3072

// Tiling
#define C     32                   // source columns per chunk
#define RB    16                   // rows per row-block (= rows per wave)
#define BT    256                  // batch per block (4/lane)
#define S1_CH (IN_DIM / C)         // 32
#define S1_RB (N_HID / RB)         // 128
#define S2_CH (SRC_DIM / C)        // 96
#define S2_RB (OUT_DIM / RB)       // 16
#define NSEG1 (S1_RB * S1_CH)      // 4096
#define NSEG2 (S2_RB * S2_CH)      // 1536
#define NCG2  16                   // k_out chunk groups (6 chunks each)
#define ZSLOT 128                  // A-tile zero page (fp16 0x0000 = +0)
#define SEG_U32 160                // segment stride (640 B)
#define ABUF_U32 ((4 * C + 1) * 128)  // 16512 u32 = 64.5 KB A-tile

// Segment format v7 (RB=16, 1-slot plane-0 + granule-2 overflow):
//   u32[0..3]   plane-0: byte r = slot for row r's edge 0 (pad 0x80)
//   overflow planes p=1..16 at u32 4+9(p-1), stride 9:
//     [0]    = 16-bit row mask (rows with n >= 2p; covers edges 2p-1, 2p)
//     [1..8] = u16 per row: 2 slot bytes for edges 2p-1, 2p (pad 0x80)
//   hdr: W = 1 + floor(max_n/2), wave-uniform.
// Rationale (R12): k_hid is DS-bytes-bound; v5 plane-0 (2 slots/row) was
// 36% pad reads. v7: 1/row (80% real) -> E[reads]/row 2.49 -> 2.12.
// LESSONS: R1 plane-0 unconditional (vector gating ~70 VALU/slot).
// R4: no long-lived preload arrays (acc scratch spill, 9297us).
// R8/R9/R10 CONFIRMED: occupancy limiter = UNIFIED VGPR+AGPR file; accs in
// AGPRs uncounted by VGPR_Count; <=64 TOTAL regs => 32 waves/CU.
// R10 (241us): fp16-packed acc (32 regs at RB=16) -> k_hid 2 blocks/CU.
// R11 (~null): k_out cg 8->16 gain offset by doubled partials traffic.

#define RFL(x) __builtin_amdgcn_readfirstlane((uint32_t)(x))

typedef _Float16 h2 __attribute__((ext_vector_type(2)));

// ---------------------------------------------------------------------------
// k_prep v2: build segment in LDS scratch (self-initialized 0x80 -> no
// global memset kernel), coalesced copy-out. 4 waves/block, 1 seg/wave.
// Grid is exact (5632 waves = 1408 blocks); no early-return divergence.
// ---------------------------------------------------------------------------
__global__ __launch_bounds__(256) void k_prep(const int* __restrict__ mat,
                       uint32_t* __restrict__ seg1, uint32_t* __restrict__ seg2,
                       uint32_t* __restrict__ hdr1, uint32_t* __restrict__ hdr2) {
    __shared__ uint32_t lseg[4][SEG_U32];
    int wid  = (blockIdx.x * blockDim.x + threadIdx.x) >> 6;
    int wv   = threadIdx.x >> 6;            // 0..3
    int lane = threadIdx.x & 63;
    if (wid >= NSEG1 + NSEG2) return;       // never taken (exact grid)

    int row0, col0;
    uint32_t *seg, *hdr;
    if (wid < NSEG1) {
        int rb = wid / S1_CH, ch = wid % S1_CH;
        row0 = rb * RB;          col0 = ch * C;
        seg = seg1 + (size_t)wid * SEG_U32;  hdr = hdr1 + wid;
    } else {
        int s  = wid - NSEG1;
        int rb = s / S2_CH, ch = s % S2_CH;
        row0 = N_HID + rb * RB;  col0 = ch * C;
        seg = seg2 + (size_t)s * SEG_U32;    hdr = hdr2 + s;
    }

    uint32_t* ls = lseg[wv];
    // Phase A: pad-fill the whole segment (all 64 lanes)
    for (int k = lane; k < SEG_U32; k += 64) ls[k] = 0x80808080u;
    __asm__ volatile("s_waitcnt lgkmcnt(0)" ::: "memory");
    __builtin_amdgcn_sched_barrier(0);

    // Phase B: lanes<16 build their row's records (byte writes into LDS)
    int n = 0;
    if (lane < RB) {
        const int4* m4 = (const int4*)(mat + (size_t)(row0 + lane) * SRC_DIM + col0);
        uint8_t* sb = (uint8_t*)ls;
        #pragma unroll
        for (int cc = 0; cc < 8; cc++) {
            int4 q4 = m4[cc];
            int codes[4] = {q4.x, q4.y, q4.z, q4.w};
            #pragma unroll
            for (int k = 0; k < 4; k++) {
                int code = codes[k];
                if (code != 0) {
                    int c = cc * 4 + k;
                    uint8_t slot = (uint8_t)((code - 1) * C + c);
                    if (n == 0) {
                        sb[lane] = slot;                   // plane-0 byte r
                    } else {
                        int jj = n - 1;                    // overflow index
                        int pl = jj >> 1;                  // 0-based ov plane
                        sb[(size_t)(4 + 9 * pl + 1 + (lane >> 1)) * 4
                           + (lane & 1) * 2 + (jj & 1)] = slot;
                    }
                    n++;
                }
            }
        }
    }
    int m = n;
    #pragma unroll
    for (int d = 1; d < 64; d <<= 1) m = max(m, __shfl_xor(m, d));
    uint32_t Wv = 1u + (uint32_t)(m >> 1);

    for (uint32_t p = 1; p < Wv; p++) {
        unsigned long long b = __ballot(n >= (int)(2 * p));
        if (lane == 0) ls[4 + 9 * (p - 1)] = (uint32_t)(b & 0xFFFFu);
    }
    __asm__ volatile("s_waitcnt lgkmcnt(0)" ::: "memory");
    __builtin_amdgcn_sched_barrier(0);

    // Phase C: coalesced copy-out
    for (int k = lane; k < SEG_U32; k += 64) seg[k] = ls[k];
    if (lane == 0) *hdr = Wv;
}

// ---------------------------------------------------------------------------
// k_xt: transpose x[8192][1024] -> x_t[1024][8192] (fp32), 64x64 LDS tiles.
// ---------------------------------------------------------------------------
__global__ __launch_bounds__(256) void k_xt(const float* __restrict__ x,
                                            float* __restrict__ x_t) {
    __shared__ float t[64][65];
    const int b0 = blockIdx.x * 64, c0 = blockIdx.y * 64;
    {
        int r  = threadIdx.x >> 4;
        int cq = (threadIdx.x & 15) * 4;
        #pragma unroll
        for (int k = 0; k < 4; k++) {
            int rr = r + 16 * k;
            float4 v = *(const float4*)&x[(size_t)(b0 + rr) * IN_DIM + c0 + cq];
            t[rr][cq + 0] = v.x; t[rr][cq + 1] = v.y;
            t[rr][cq + 2] = v.z; t[rr][cq + 3] = v.w;
        }
    }
    __syncthreads();
    {
        int bq  = (threadIdx.x & 15) * 4;
        int cc0 = threadIdx.x >> 4;
        #pragma unroll
        for (int k = 0; k < 4; k++) {
            int cc = cc0 + 16 * k;
            float4 v;
            v.x = t[bq + 0][cc]; v.y = t[bq + 1][cc];
            v.z = t[bq + 2][cc]; v.w = t[bq + 3][cc];
            *(float4*)&x_t[(size_t)(c0 + cc) * BATCH + b0 + bq] = v;
        }
    }
}

// pack two floats as fp16 pair (v_cvt_pkrtz_f16_f32, 1 instr)
__device__ __forceinline__ uint32_t pkh(float a, float b) {
    auto r = __builtin_amdgcn_cvt_pkrtz(a, b);
    return __builtin_bit_cast(uint32_t, r);
}

__device__ __forceinline__ float rcp_f(float x) { return __builtin_amdgcn_rcpf(x); }

// write 4 activation slots for column c, 4 batches per lane (v pre-scaled by w).
// Values stored as fp16 pairs. Trans budget/elem: 1 v_exp + 2 v_rcp.
__device__ __forceinline__ void write_acts4(uint32_t* As, int c, int lane, float4 v) {
    *(uint2*)&As[(size_t)(0 * C + c) * 128 + 2 * lane] =
        make_uint2(pkh(v.x, v.y), pkh(v.z, v.w));
    *(uint2*)&As[(size_t)(1 * C + c) * 128 + 2 * lane] =
        make_uint2(pkh(fmaxf(v.x, 0.0f), fmaxf(v.y, 0.0f)),
                   pkh(fmaxf(v.z, 0.0f), fmaxf(v.w, 0.0f)));
    float ex = __expf(-v.x), ey = __expf(-v.y);
    float ez = __expf(-v.z), ew = __expf(-v.w);
    float tx = fmaf(2.0f, rcp_f(fmaf(ex, ex, 1.0f)), -1.0f);
    float ty = fmaf(2.0f, rcp_f(fmaf(ey, ey, 1.0f)), -1.0f);
    float tz = fmaf(2.0f, rcp_f(fmaf(ez, ez, 1.0f)), -1.0f);
    float tw = fmaf(2.0f, rcp_f(fmaf(ew, ew, 1.0f)), -1.0f);
    *(uint2*)&As[(size_t)(2 * C + c) * 128 + 2 * lane] =
        make_uint2(pkh(tx, ty), pkh(tz, tw));
    float sx = rcp_f(1.0f + ex), sy = rcp_f(1.0f + ey);
    float sz = rcp_f(1.0f + ez), sw = rcp_f(1.0f + ew);
    *(uint2*)&As[(size_t)(3 * C + c) * 128 + 2 * lane] =
        make_uint2(pkh(sx, sy), pkh(sz, sw));
}

// one slot: ds_read_b64 -> 2 v_pk_add_f16 (4 batches/lane). ~3 VALU total.
#define SLOT_ACC(R, S)                                                         \
    {                                                                          \
        uint2 q_ = *(const uint2*)&As[(size_t)(S) * 128 + 2 * lane];           \
        accA[R] += __builtin_bit_cast(h2, q_.x);                               \
        accB[R] += __builtin_bit_cast(h2, q_.y);                               \
    }

// v7: plane-0 = 1 slot/row (4 words, 16 slots, pads -> zero page);
// overflow planes granule-2, scalar-gated, loaded INSIDE guard (R4 lesson).
#define EDGE_PLANES(SEGBASE, WVAL)                                             \
    {                                                                          \
        const uint32_t* sp_ = (SEGBASE);                                       \
        _Pragma("unroll")                                                      \
        for (int i = 0; i < 4; i++) {                                          \
            uint32_t g = RFL(sp_[i]);                                          \
            SLOT_ACC(4 * i + 0, g & 255u)                                      \
            SLOT_ACC(4 * i + 1, (g >> 8) & 255u)                               \
            SLOT_ACC(4 * i + 2, (g >> 16) & 255u)                              \
            SLOT_ACC(4 * i + 3, g >> 24)                                       \
        }                                                                      \
        _Pragma("unroll 1")                                                    \
        for (uint32_t p = 1; p < (WVAL); p++) {                                \
            const uint32_t* pp_ = sp_ + 4 + 9 * (p - 1);                       \
            uint32_t mask = RFL(pp_[0]);                                       \
            _Pragma("unroll")                                                  \
            for (int r = 0; r < RB; r++) {                                     \
                if (mask & (1u << r)) {                                        \
                    uint32_t h_ = RFL(pp_[1 + (r >> 1)]);                      \
                    uint32_t u_ = (r & 1) ? (h_ >> 16) : h_;                   \
                    SLOT_ACC(r, u_ & 255u)                                     \
                    SLOT_ACC(r, (u_ >> 8) & 255u)                              \
                }                                                              \
            }                                                                  \
        }                                                                      \
    }

// ---------------------------------------------------------------------------
// Stage 1: 16 waves x 16 rows = 256 rows; 256 batches; 16 chunks per block.
// Grid (32 tiles, 8 row splits, 2 chunk groups) = 512 blocks = 2/CU
// (acc fp16-packed: 32 regs; total <=64 => 32 waves/CU; LDS 2x66KB).
// Output: fp16 partial hidden plane per chunk-group (summed in k_out loads).
// ---------------------------------------------------------------------------
__global__ __launch_bounds__(1024, 8) void k_hid(const float* __restrict__ x_t,
                                                 const float* __restrict__ wp,
                                                 const uint32_t* __restrict__ seg1,
                                                 const uint32_t* __restrict__ hdr1,
                                                 uint16_t* __restrict__ hidden_t) {
    __shared__ uint32_t As[ABUF_U32];           // 64.5 KB

    const float w  = wp[0];
    const int tile = blockIdx.x;                // 0..31
    const int cgh  = blockIdx.z;                // 0..1 (chunk group)
    const int lane = threadIdx.x & 63;
    const int wv   = __builtin_amdgcn_readfirstlane(threadIdx.x >> 6); // 0..15
    const int rb   = blockIdx.y * 16 + wv;      // row-block 0..127
    const int b0   = tile * BT;
    const int c0   = cgh * (S1_CH / 2);         // first chunk of group

    if (threadIdx.x < 128) As[ZSLOT * 128 + threadIdx.x] = 0u;

    h2 accA[RB], accB[RB];
    const h2 hz = {(_Float16)0.0f, (_Float16)0.0f};
    #pragma unroll
    for (int r = 0; r < RB; r++) { accA[r] = hz; accB[r] = hz; }

    // prefetch first chunk: each wave owns 2 columns, 4 batches/lane
    float4 v[2];
    #pragma unroll
    for (int j = 0; j < 2; j++) {
        int gcol = c0 * C + wv * 2 + j;
        const float2* xp = (const float2*)&x_t[(size_t)gcol * BATCH + b0];
        float2 u0 = xp[lane], u1 = xp[64 + lane];
        v[j] = make_float4(w * u0.x, w * u0.y, w * u1.x, w * u1.y);
    }

    #pragma unroll 1
    for (int cj = 0; cj < S1_CH / 2; cj++) {
        int ch = c0 + cj;
        __syncthreads();                        // edge(ch-1) done (WAR)
        write_acts4(As, wv * 2 + 0, lane, v[0]);
        write_acts4(As, wv * 2 + 1, lane, v[1]);
        __syncthreads();                        // acts visible
        if (cj + 1 < S1_CH / 2) {               // prefetch next chunk
            #pragma unroll
            for (int j = 0; j < 2; j++) {
                int gcol = (ch + 1) * C + wv * 2 + j;
                const float2* xp = (const float2*)&x_t[(size_t)gcol * BATCH + b0];
                float2 u0 = xp[lane], u1 = xp[64 + lane];
                v[j] = make_float4(w * u0.x, w * u0.y, w * u1.x, w * u1.y);
            }
        }
        int sidx = rb * S1_CH + ch;
        uint32_t W = RFL(hdr1[sidx]);
        EDGE_PLANES(seg1 + (size_t)sidx * SEG_U32, W)
    }

    uint16_t* hout = hidden_t + (size_t)cgh * N_HID * BATCH;
    const int row0 = rb * RB;
    #pragma unroll
    for (int r = 0; r < RB; r++) {              // acc is already fp16-packed
        *(uint32_t*)&hout[(size_t)(row0 + r) * BATCH + b0 + 2 * lane] =
            __builtin_bit_cast(uint32_t, accA[r]);
        *(uint32_t*)&hout[(size_t)(row0 + r) * BATCH + b0 + 128 + 2 * lane] =
            __builtin_bit_cast(uint32_t, accB[r]);
    }
}

// source loader for stage 2: x_t fp32, or SUM of 2 fp16 partial hidden planes
__device__ __forceinline__ float4 load_src4(const float* __restrict__ x_t,
                                            const uint16_t* __restrict__ hidden_t,
                                            int gcol, int b0, int lane, float w) {
    if (gcol < IN_DIM) {
        const float2* xp = (const float2*)&x_t[(size_t)gcol * BATCH + b0];
        float2 u0 = xp[lane], u1 = xp[64 + lane];
        return make_float4(w * u0.x, w * u0.y, w * u1.x, w * u1.y);
    } else {
        const uint16_t* hp = hidden_t + (size_t)(gcol - IN_DIM) * BATCH + b0;
        const uint16_t* hq = hp + (size_t)N_HID * BATCH;   // partial plane 1
        uint32_t a0 = *(const uint32_t*)&hp[2 * lane];
        uint32_t a1 = *(const uint32_t*)&hp[128 + 2 * lane];
        uint32_t c0 = *(const uint32_t*)&hq[2 * lane];
        uint32_t c1 = *(const uint32_t*)&hq[128 + 2 * lane];
        h2 s0 = __builtin_bit_cast(h2, a0) + __builtin_bit_cast(h2, c0);
        h2 s1 = __builtin_bit_cast(h2, a1) + __builtin_bit_cast(h2, c1);
        return make_float4(w * (float)s0.x, w * (float)s0.y,
                           w * (float)s1.x, w * (float)s1.y);
    }
}

// ---------------------------------------------------------------------------
// Stage 2: 16 waves x 16 rows = ALL 256 out rows; 256 batches per block.
// Grid (32 tiles, 16 chunk groups of 6) = 512 blocks = 2/CU.
// Partials fp16-packed [cg16][row][b/2].
// ---------------------------------------------------------------------------
__global__ __launch_bounds__(1024, 8) void k_out(const float* __restrict__ x_t,
                                                 const uint16_t* __restrict__ hidden_t,
                                                 const float* __restrict__ wp,
                                                 const uint32_t* __restrict__ seg2,
                                                 const uint32_t* __restrict__ hdr2,
                                                 uint32_t* __restrict__ partials) {
    __shared__ uint32_t As[ABUF_U32];

    const float w  = wp[0];
    const int tile = blockIdx.x;                // 0..31
    const int cg   = blockIdx.y;                // 0..15
    const int lane = threadIdx.x & 63;
    const int wv   = __builtin_amdgcn_readfirstlane(threadIdx.x >> 6); // 0..15
    const int b0   = tile * BT;
    const int nch  = S2_CH / NCG2;              // 6 chunks per block

    if (threadIdx.x < 128) As[ZSLOT * 128 + threadIdx.x] = 0u;

    h2 accA[RB], accB[RB];
    const h2 hz = {(_Float16)0.0f, (_Float16)0.0f};
    #pragma unroll
    for (int r = 0; r < RB; r++) { accA[r] = hz; accB[r] = hz; }

    float4 v[2];
    #pragma unroll
    for (int j = 0; j < 2; j++)
        v[j] = load_src4(x_t, hidden_t, (cg * nch) * C + wv * 2 + j, b0, lane, w);

    #pragma unroll 1
    for (int cj = 0; cj < nch; cj++) {
        int ch = cg * nch + cj;
        __syncthreads();
        write_acts4(As, wv * 2 + 0, lane, v[0]);
        write_acts4(As, wv * 2 + 1, lane, v[1]);
        __syncthreads();
        if (cj + 1 < nch) {
            #pragma unroll
            for (int j = 0; j < 2; j++)
                v[j] = load_src4(x_t, hidden_t, (ch + 1) * C + wv * 2 + j, b0, lane, w);
        }
        int sidx = wv * S2_CH + ch;              // wv = row-block 0..15
        uint32_t W = RFL(hdr2[sidx]);
        EDGE_PLANES(seg2 + (size_t)sidx * SEG_U32, W)
    }

    #pragma unroll
    for (int r = 0; r < RB; r++) {
        size_t base = ((size_t)cg * OUT_DIM + wv * RB + r) * (BATCH / 2) + (b0 >> 1);
        partials[base + lane]      = __builtin_bit_cast(uint32_t, accA[r]);
        partials[base + 64 + lane] = __builtin_bit_cast(uint32_t, accB[r]);
    }
}

// ---------------------------------------------------------------------------
// k_sum: reduce 16 fp16-packed partial planes + transpose -> out[b][r].
// Block: 128 batches x 16 rows. Grid (64, 16).
// ---------------------------------------------------------------------------
__global__ __launch_bounds__(256) void k_sum(const uint32_t* __restrict__ partials,
                                             float* __restrict__ out) {
    __shared__ float t[16][130];
    const int b0 = blockIdx.x * 128, r0 = blockIdx.y * 16;
    const int lane = threadIdx.x & 63;
    const int g4   = threadIdx.x >> 6;          // 0..3

    #pragma unroll
    for (int k = 0; k < 4; k++) {
        int rr = g4 * 4 + k;
        float sx = 0.0f, sy = 0.0f;
        #pragma unroll
        for (int cg = 0; cg < NCG2; cg++) {
            uint32_t q = partials[((size_t)cg * OUT_DIM + r0 + rr) * (BATCH / 2)
                                  + (b0 >> 1) + lane];
            h2 h = __builtin_bit_cast(h2, q);
            sx += (float)h.x;
            sy += (float)h.y;
        }
        t[rr][2 * lane]     = sx;
        t[rr][2 * lane + 1] = sy;
    }
    __syncthreads();
    #pragma unroll
    for (int k = 0; k < 2; k++) {
        int idx = threadIdx.x + 256 * k;        // 0..511
        int bb = idx >> 2, rq = idx & 3;
        float4 v;
        v.x = t[rq * 4 + 0][bb];
        v.y = t[rq * 4 + 1][bb];
        v.z = t[rq * 4 + 2][bb];
        v.w = t[rq * 4 + 3][bb];
        *(float4*)&out[(size_t)(b0 + bb) * OUT_DIM + r0 + rq * 4] = v;
    }
}

// ---------------------------------------------------------------------------
extern "C" void kernel_launch(void* const* d_in, const int* in_sizes, int n_in,
                              void* d_out, int out_size, void* d_ws, size_t ws_size,
                              hipStream_t stream) {
    const float* x   = (const float*)d_in[0];
    const float* w   = (const float*)d_in[1];
    const int*   mat = (const int*)d_in[2];
    float* out = (float*)d_out;

    uint8_t* ws = (uint8_t*)d_ws;
    size_t off = 0;
    uint16_t* hidden_t = (uint16_t*)(ws + off);
    off += (size_t)2 * BATCH * N_HID * 2;                                      // 67.1 MB (2 fp16 planes)
    float* x_t = (float*)(ws + off);        off += (size_t)IN_DIM * BATCH * 4; // 33.6 MB
    uint32_t* seg1 = (uint32_t*)(ws + off); off += (size_t)NSEG1 * SEG_U32 * 4;//  2.62 MB
    uint32_t* seg2 = (uint32_t*)(ws + off); off += (size_t)NSEG2 * SEG_U32 * 4;//  0.98 MB
    uint32_t* hdr1 = (uint32_t*)(ws + off); off += (size_t)NSEG1 * 4;
    uint32_t* hdr2 = (uint32_t*)(ws + off); off += (size_t)NSEG2 * 4;
    uint32_t* partials = (uint32_t*)(ws + off);
    off += (size_t)NCG2 * OUT_DIM * (BATCH / 2) * 4;                           // 67.1 MB
    (void)ws_size; (void)in_sizes; (void)n_in; (void)out_size;

    // v7 k_prep self-initializes each segment in LDS -> no global memset.
    {
        int nseg = NSEG1 + NSEG2;                   // 5632 waves, exact grid
        k_prep<<<(nseg + 3) / 4, 256, 0, stream>>>(mat, seg1, seg2, hdr1, hdr2);
    }
    {
        dim3 g(BATCH / 64, IN_DIM / 64);            // 128 x 16
        k_xt<<<g, 256, 0, stream>>>(x, x_t);
    }
    {
        dim3 g(BATCH / BT, 8, 2);                   // 32 x 8 x 2 = 512 blocks
        k_hid<<<g, 1024, 0, stream>>>(x_t, w, seg1, hdr1, hidden_t);
    }
    {
        dim3 g(BATCH / BT, NCG2);                   // 32 x 16 = 512 blocks
        k_out<<<g, 1024, 0, stream>>>(x_t, hidden_t, w, seg2, hdr2, partials);
    }
    {
        dim3 g(BATCH / 128, OUT_DIM / 16);          // 64 x 16 = 1024 blocks
        k_sum<<<g, 256, 0, stream>>>(partials, out);
    }
}